// Round 16
// baseline (800.376 us; speedup 1.0000x reference)
//
#include <hip/hip_runtime.h>
#include <cstddef>

#define V_N 49152
#define E_N 442368
#define E_PAD 589824   // E_N + 3*V_N: worst-case row padding to multiple of 4
#define GEPS 1e-5f
#define CO 256
#define TD 256

typedef _Float16 h16;
typedef _Float16 h8v __attribute__((ext_vector_type(8)));
typedef float f4v __attribute__((ext_vector_type(4)));

// terms layout: [slot][slice(8)][V][32ch], quad q of vertex v stored at
// 16B-slot (q ^ ((v>>1)&3)) within the 64B row. Swizzle sites: gn*_apply
// write, spmv gather/write, GEMM ds_read (fq ^ ((fr>>1)&3)) -- all matched.

__device__ __forceinline__ void gload_lds16(const void* g, void* l) {
    __builtin_amdgcn_global_load_lds(
        (const __attribute__((address_space(1))) unsigned int*)g,
        (__attribute__((address_space(3))) unsigned int*)l, 16, 0, 0);
}

// ---------------- CSR build ----------------
__global__ void count_edges(const int* __restrict__ row, int* __restrict__ cnt) {
    int e = blockIdx.x * blockDim.x + threadIdx.x;
    if (e < E_N) atomicAdd(&cnt[row[e]], 1);
}

// rows padded to multiple of 4 edges (pad slots pre-zeroed in ep)
__global__ void scan_rowptr(int* __restrict__ cnt, int* __restrict__ rowptr) {
    __shared__ int part[1024];
    const int CHUNK = V_N / 1024;  // 48
    int t = threadIdx.x;
    int base = t * CHUNK;
    int s = 0;
    for (int i = 0; i < CHUNK; ++i) s += (cnt[base + i] + 3) & ~3;
    part[t] = s;
    __syncthreads();
    for (int off = 1; off < 1024; off <<= 1) {
        int v = part[t];
        int add = (t >= off) ? part[t - off] : 0;
        __syncthreads();
        part[t] = v + add;
        __syncthreads();
    }
    int run = (t == 0) ? 0 : part[t - 1];
    for (int i = 0; i < CHUNK; ++i) {
        int c = cnt[base + i];
        rowptr[base + i] = run;
        cnt[base + i] = run;   // cursor init for fill pass
        run += (c + 3) & ~3;
    }
    if (t == 1023) rowptr[V_N] = run;
}

// packed edge: {col, val bits} -> one 8B slot per edge
__global__ void fill_csr(const int* __restrict__ row, const int* __restrict__ col,
                         const float* __restrict__ vals, int* __restrict__ cursor,
                         int2* __restrict__ ep) {
    int e = blockIdx.x * blockDim.x + threadIdx.x;
    if (e < E_N) {
        int r = row[e];
        int slot = atomicAdd(&cursor[r], 1);
        ep[slot] = make_int2(col[e], __float_as_int(vals[e]));
    }
}

// ---------------- weight prep: w[k][c][f] fp32 -> MFMA fragment order -------------
// wf[kstep][ntile][lane][8]: lane=(fq<<4)|fr holds w[ks*32+fq*8+j][nt*16+fr].
__global__ void wprep_frag(const float* __restrict__ w, h16* __restrict__ wf) {
    int ks = blockIdx.x, nt = blockIdx.y, lane = threadIdx.x;
    int fr = lane & 15, fq = lane >> 4;
    int f = nt * 16 + fr;
    h8v o;
#pragma unroll
    for (int jj = 0; jj < 8; ++jj) {
        int kc = ks * 32 + fq * 8 + jj;
        o[jj] = (h16)w[(size_t)kc * CO + f];
    }
    *(h8v*)&wf[(((size_t)ks * 16 + nt) * 64 + lane) * 8] = o;
}

// ---------------- GroupNorm stats (register accumulation, per-block partials) ----
template <int C>
__global__ void gn_stats2(const float* __restrict__ x, const float* __restrict__ tvec,
                          float* __restrict__ part) {
    __shared__ float ls[8], lss[8];
    int t = threadIdx.x;
    if (t < 8) { ls[t] = 0.f; lss[t] = 0.f; }
    __syncthreads();
    const int total4 = V_N * (C / 4);
    const int cmask = (C / 4) - 1;
    const int stride = gridDim.x * blockDim.x;  // multiple of 64
    int i0 = blockIdx.x * blockDim.x + t;
    const int c4 = i0 & cmask;  // constant across the loop
    float t0 = 0.f, t1 = 0.f, t2 = 0.f, t3 = 0.f;
    if (tvec) {
        t0 = tvec[c4 * 4 + 0]; t1 = tvec[c4 * 4 + 1];
        t2 = tvec[c4 * 4 + 2]; t3 = tvec[c4 * 4 + 3];
    }
    float s = 0.f, ss = 0.f;
    for (int i = i0; i < total4; i += stride) {
        float4 v = ((const float4*)x)[i];
        v.x += t0; v.y += t1; v.z += t2; v.w += t3;
        s  += v.x + v.y + v.z + v.w;
        ss += v.x * v.x + v.y * v.y + v.z * v.z + v.w * v.w;
    }
    constexpr int GL = (C == 128) ? 4 : 8;
#pragma unroll
    for (int off = 1; off < GL; off <<= 1) {
        s  += __shfl_xor(s, off);
        ss += __shfl_xor(ss, off);
    }
    int lane = t & 63;
    if ((lane & (GL - 1)) == 0) {
        int g = c4 >> ((C == 128) ? 2 : 3);
        atomicAdd(&ls[g], s);
        atomicAdd(&lss[g], ss);
    }
    __syncthreads();
    if (t < 16) part[blockIdx.x * 16 + t] = (t < 8) ? ls[t] : lss[t - 8];
}

#define GN_BLOCKS 512

__global__ void gn_reduce(const float* __restrict__ part, float* __restrict__ stats,
                          int nb) {
    __shared__ float acc[16];
    int t = threadIdx.x;  // 256
    if (t < 16) acc[t] = 0.f;
    __syncthreads();
    int idx = t & 15;
    float s = 0.f;
    for (int j = t >> 4; j < nb; j += 16) s += part[j * 16 + idx];
    atomicAdd(&acc[idx], s);
    __syncthreads();
    if (t < 16) stats[t] = acc[t];
}

// ---------------- GN1 apply + SiLU -> slot0 slices 0..3; raw cast -> slices 4..7 --
__global__ void gn1_apply(const float* __restrict__ x, const float* __restrict__ stats,
                          const float* __restrict__ gamma, const float* __restrict__ beta,
                          h16* __restrict__ terms) {
    const float Ng = (float)V_N * 16.f;   // C=128: V*C/8
    const int total = V_N * 16;
    for (int i = blockIdx.x * blockDim.x + threadIdx.x; i < total;
         i += gridDim.x * blockDim.x) {
        int v = i >> 4, c8 = i & 15;
        float4 xa = ((const float4*)x)[v * 32 + c8 * 2];
        float4 xb = ((const float4*)x)[v * 32 + c8 * 2 + 1];
        float in[8] = {xa.x, xa.y, xa.z, xa.w, xb.x, xb.y, xb.z, xb.w};
        h8v o, oc;
#pragma unroll
        for (int j = 0; j < 8; ++j) {
            int c = c8 * 8 + j;
            int g = c >> 4;
            float mu = stats[g] / Ng;
            float var = stats[8 + g] / Ng - mu * mu;
            float rs = rsqrtf(var + GEPS);
            float y = (in[j] - mu) * rs * gamma[c] + beta[c];
            y = y / (1.f + expf(-y));
            o[j] = (h16)y;
            oc[j] = (h16)in[j];
        }
        int qsl = ((c8 & 3) ^ ((v >> 1) & 3)) * 8;
        int slice = c8 >> 2;
        *(h8v*)&terms[((size_t)slice * V_N + v) * 32 + qsl] = o;
        *(h8v*)&terms[((size_t)(4 + slice) * V_N + v) * 32 + qsl] = oc;
    }
}

// ---------------- GN2 apply + SiLU -> slot0 slices 0..7 (full 256) ----------------
__global__ void gn2_apply(const float* __restrict__ x, const float* __restrict__ tvec,
                          const float* __restrict__ stats, const float* __restrict__ gamma,
                          const float* __restrict__ beta, h16* __restrict__ terms) {
    const float Ng = (float)V_N * 32.f;   // C=256: V*C/8
    const int total = V_N * 32;
    for (int i = blockIdx.x * blockDim.x + threadIdx.x; i < total;
         i += gridDim.x * blockDim.x) {
        int v = i >> 5, c8 = i & 31;
        float4 xa = ((const float4*)x)[v * 64 + c8 * 2];
        float4 xb = ((const float4*)x)[v * 64 + c8 * 2 + 1];
        float in[8] = {xa.x, xa.y, xa.z, xa.w, xb.x, xb.y, xb.z, xb.w};
        h8v o;
#pragma unroll
        for (int j = 0; j < 8; ++j) {
            int c = c8 * 8 + j;
            int g = c >> 5;
            float mu = stats[g] / Ng;
            float var = stats[8 + g] / Ng - mu * mu;
            float rs = rsqrtf(var + GEPS);
            float val = in[j] + tvec[c];
            float y = (val - mu) * rs * gamma[c] + beta[c];
            y = y / (1.f + expf(-y));
            o[j] = (h16)y;
        }
        int qsl = ((c8 & 3) ^ ((v >> 1) & 3)) * 8;
        int slice = c8 >> 2;
        *(h8v*)&terms[((size_t)slice * V_N + v) * 32 + qsl] = o;
    }
}

// ---------------- time embedding MLP ----------------
__global__ void time_mlp(const float* __restrict__ te, const float* __restrict__ wt,
                         const float* __restrict__ bt, float* __restrict__ tvec) {
    __shared__ float s[TD];
    int f = threadIdx.x;
    float v = te[f];
    s[f] = v / (1.f + expf(-v));
    __syncthreads();
    float acc = bt[f];
    for (int t = 0; t < TD; ++t) acc += s[t] * wt[t * CO + f];
    tvec[f] = acc;
}

// ---------------- SpMV, slice-parallel XCD-pinned ----------------
// slice = bid&7 (-> XCD bid&7 by round-robin dispatch): slice footprint
// V*64B = 3.1MB fits that XCD's 4MB L2 -> gathers are L2-local.
// 4-lane group per vertex (lane q = quad), 4 edges in flight, NO cross-lane
// reduce. Rows padded to 4 (pad col=0/val=0 -> hot line, contributes 0).
template <bool RECUR>
__global__ void spmv_slice(const int* __restrict__ rowptr, const int2* __restrict__ ep,
                           h16* __restrict__ terms, int zs, int ps, int ds) {
    const int slice = blockIdx.x & 7;
    const int wid = threadIdx.x >> 6, lane = threadIdx.x & 63;
    const int eg = lane >> 2, q = lane & 3;
    const int v = (blockIdx.x >> 3) * 64 + wid * 16 + eg;
    const h16* zb = terms + ((size_t)(zs * 8 + slice) * V_N) * 32;
    h16* db = terms + ((size_t)(ds * 8 + slice) * V_N) * 32;
    int s = rowptr[v], e = rowptr[v + 1];   // multiples of 4
    float acc[8];
#pragma unroll
    for (int i = 0; i < 8; ++i) acc[i] = 0.f;
    const int4* e4 = (const int4*)(ep + s);  // aligned (s % 4 == 0)
    int n4 = (e - s) >> 1;                   // int4 count (multiple of 2)
    for (int i = 0; i < n4; i += 2) {
        int4 a0 = e4[i], a1 = e4[i + 1];
        h8v z0 = *(const h8v*)&zb[(size_t)a0.x * 32 + ((q ^ ((a0.x >> 1) & 3)) * 8)];
        h8v z1 = *(const h8v*)&zb[(size_t)a0.z * 32 + ((q ^ ((a0.z >> 1) & 3)) * 8)];
        h8v z2 = *(const h8v*)&zb[(size_t)a1.x * 32 + ((q ^ ((a1.x >> 1) & 3)) * 8)];
        h8v z3 = *(const h8v*)&zb[(size_t)a1.z * 32 + ((q ^ ((a1.z >> 1) & 3)) * 8)];
        float v0 = __int_as_float(a0.y), v1 = __int_as_float(a0.w);
        float v2 = __int_as_float(a1.y), v3 = __int_as_float(a1.w);
#pragma unroll
        for (int k = 0; k < 8; ++k)
            acc[k] += v0 * (float)z0[k] + v1 * (float)z1[k] +
                      v2 * (float)z2[k] + v3 * (float)z3[k];
    }
    size_t base = (size_t)v * 32 + ((q ^ ((v >> 1) & 3)) * 8);
    h8v o;
    if (RECUR) {
        const h16* pb = terms + ((size_t)(ps * 8 + slice) * V_N) * 32;
        h8v pv = *(const h8v*)&pb[base];
#pragma unroll
        for (int i = 0; i < 8; ++i) o[i] = (h16)(2.f * acc[i] - (float)pv[i]);
    } else {
#pragma unroll
        for (int i = 0; i < 8; ++i) o[i] = (h16)acc[i];
    }
    *(h8v*)&db[base] = o;
}

// ---------------- MFMA fp16 GEMM: 64x128 tile, 6 blocks/CU, frag-stream B --------
// TLP lever: same staged-A bytes as the 128x128 version (each A-row read by its
// 2 XCD-paired N-half blocks either way), but grid 1536 = 6 blocks/CU (vs 3) ->
// 2x independent stall-streams. LDS 2x4KB; acc 4x2 (VGPR ~60 < 85 cap @ 6/CU).
// Per wave per K-step: 1 gload_lds (A quarter, 1KB contiguous) + 2 B-frag loads
// (1KB contiguous each, L2-hot) + 8 MFMA. ds_read slot matches layout swizzle.
// MODE: 0 = store, 1 = accumulate, 2 = out = bias + acc (residual fuse).
// DUAL: blockIdx.y==1 -> slices 4..7 (raw-x half), Wf2, out2.
template <int MODE, bool DUAL>
__global__ __launch_bounds__(256, 6) void gemm_f16(
    const h16* __restrict__ terms, const h16* __restrict__ Wf,
    const h16* __restrict__ Wf2, int kslot0, int wofs, int KC, int slsh,
    const float* __restrict__ bias, float* __restrict__ out,
    float* __restrict__ out2) {
    __shared__ h16 As[2][64 * 32];
    int sofs = 0;
    if (DUAL && blockIdx.y) { Wf = Wf2; out = out2; sofs = 4; }
    const int bid = blockIdx.x;            // 0..1535
    const int xcd = bid & 7;
    const int j = bid >> 3;                // 0..191
    const int mblk = xcd * 96 + (j >> 1);  // 0..767 (96 = (V_N/64)/8 panels/XCD)
    const int nh = j & 1;                  // N-half
    const int m0 = mblk * 64;
    const int n0 = nh * 128;
    const int tid = threadIdx.x;
    const int wid = tid >> 6, lane = tid & 63;
    const int fr = lane & 15, fq = lane >> 4;
    const int smsk = (1 << slsh) - 1;
    const h16* Wlane = Wf + ((size_t)(wofs >> 5) * 16 * 512) + (size_t)lane * 8;
    const int ntb = (n0 >> 4) + wid * 2;   // wave wid owns cols [n0+wid*32, +32)

    f4v acc[4][2];
#pragma unroll
    for (int i = 0; i < 4; ++i)
#pragma unroll
        for (int n = 0; n < 2; ++n) acc[i][n] = (f4v){0.f, 0.f, 0.f, 0.f};

    const int nt = KC >> 5;
    auto stageA = [&](int t, int buf) {
        int r8 = (kslot0 + (t >> slsh)) * 8 + ((t & smsk) + sofs);
        const h16* b = terms + ((size_t)r8 * V_N + m0) * 32;
        gload_lds16(b + (size_t)(wid * 16) * 32 + lane * 8, &As[buf][(wid * 16) * 32]);
    };
    h8v bfc[2], bfn[2];
    stageA(0, 0);
#pragma unroll
    for (int n = 0; n < 2; ++n)
        bfc[n] = *(const h8v*)&Wlane[(size_t)(ntb + n) * 512];
    __syncthreads();

    const int slot = (fq ^ ((fr >> 1) & 3)) * 8;
    for (int t = 0; t < nt; ++t) {
        const int cur = t & 1;
        h8v af[4];
#pragma unroll
        for (int i = 0; i < 4; ++i)
            af[i] = *(const h8v*)&As[cur][(i * 16 + fr) * 32 + slot];
        int tn = (t + 1 < nt) ? t + 1 : t;
        stageA(tn, cur ^ 1);
#pragma unroll
        for (int n = 0; n < 2; ++n)
            bfn[n] = *(const h8v*)&Wlane[((size_t)tn * 16 + ntb + n) * 512];
#pragma unroll
        for (int i = 0; i < 4; ++i)
#pragma unroll
            for (int n = 0; n < 2; ++n)
                acc[i][n] = __builtin_amdgcn_mfma_f32_16x16x32_f16(af[i], bfc[n],
                                                                   acc[i][n], 0, 0, 0);
        __syncthreads();
#pragma unroll
        for (int n = 0; n < 2; ++n) bfc[n] = bfn[n];
    }
#pragma unroll
    for (int i = 0; i < 4; ++i)
#pragma unroll
        for (int n = 0; n < 2; ++n)
#pragma unroll
            for (int rr = 0; rr < 4; ++rr) {
                int row = m0 + i * 16 + fq * 4 + rr;
                int col = n0 + wid * 32 + n * 16 + fr;
                size_t idx = (size_t)row * CO + col;
                if (MODE == 0) out[idx] = acc[i][n][rr];
                else if (MODE == 1) out[idx] += acc[i][n][rr];
                else out[idx] = bias[idx] + acc[i][n][rr];
            }
}

// ---------------- host orchestration ----------------
static void chain_spmv(hipStream_t s, int chunk, int k0, int kend, h16* terms,
                       const int* rp, const int2* ep) {
    for (int k = (k0 == 0 ? 1 : k0); k < kend; ++k) {
        int zs = (k - 1) % chunk, ds = k % chunk;
        if (k == 1) {
            spmv_slice<false><<<V_N / 64 * 8, 256, 0, s>>>(rp, ep, terms, zs, 0, ds);
        } else {
            int ps = (k - 2) % chunk;
            spmv_slice<true><<<V_N / 64 * 8, 256, 0, s>>>(rp, ep, terms, zs, ps, ds);
        }
    }
}

extern "C" void kernel_launch(void* const* d_in, const int* in_sizes, int n_in,
                              void* d_out, int out_size, void* d_ws, size_t ws_size,
                              hipStream_t stream) {
    const float* x    = (const float*)d_in[0];
    const float* te   = (const float*)d_in[1];
    const int*   row  = (const int*)d_in[2];
    const int*   col  = (const int*)d_in[3];
    const float* vals = (const float*)d_in[4];
    const float* wres = (const float*)d_in[5];
    const float* w1   = (const float*)d_in[6];
    const float* w2   = (const float*)d_in[7];
    const float* g1   = (const float*)d_in[8];
    const float* b1   = (const float*)d_in[9];
    const float* g2   = (const float*)d_in[10];
    const float* b2   = (const float*)d_in[11];
    const float* wt   = (const float*)d_in[12];
    const float* bt   = (const float*)d_in[13];
    float* out = (float*)d_out;

    const int chunk = 8;
    const size_t slot_b = (size_t)V_N * 256 * 2;          // 25.2 MB per k-slot
    const size_t res_b  = (size_t)V_N * 256 * 4;          // 50.3 MB
    const size_t csr_b  = (size_t)(V_N + V_N + 1) * 4 + (size_t)E_PAD * 8;
    const size_t wt_b   = (size_t)(1024 + 2048 + 1024) * CO * 2;
    const size_t misc_b = 8192 + (size_t)GN_BLOCKS * 16 * 4;
    if (ws_size < (size_t)chunk * slot_b + res_b + csr_b + wt_b + misc_b) return;

    char* p = (char*)d_ws;
    h16* terms = (h16*)p;              p += (size_t)chunk * slot_b;
    float* resbuf = (float*)p;         p += res_b;
    h16* w1f = (h16*)p;                p += (size_t)1024 * CO * 2;
    h16* w2f = (h16*)p;                p += (size_t)2048 * CO * 2;
    h16* wrf = (h16*)p;                p += (size_t)1024 * CO * 2;
    int* cnt = (int*)p;                p += (size_t)V_N * 4;
    int* rp  = (int*)p;                p += (size_t)(V_N + 1) * 4;
    int2* ep = (int2*)p;               p += (size_t)E_PAD * 8;
    float* stats = (float*)p;          p += 64;
    float* tv = (float*)p;             p += 1024;
    float* gpart = (float*)p;          p += (size_t)GN_BLOCKS * 16 * 4;

    // CSR build (rows padded to multiple of 4; pad slots are {0, 0.0f})
    hipMemsetAsync(cnt, 0, V_N * sizeof(int), stream);
    hipMemsetAsync(ep, 0, (size_t)E_PAD * 8, stream);
    count_edges<<<E_N / 256, 256, 0, stream>>>(row, cnt);
    scan_rowptr<<<1, 1024, 0, stream>>>(cnt, rp);
    fill_csr<<<E_N / 256, 256, 0, stream>>>(row, col, vals, cnt, ep);

    // weight prep: MFMA fragment order
    wprep_frag<<<dim3(32, 16), 64, 0, stream>>>(w1, w1f);
    wprep_frag<<<dim3(64, 16), 64, 0, stream>>>(w2, w2f);
    wprep_frag<<<dim3(32, 16), 64, 0, stream>>>(wres, wrf);

    // time embedding
    time_mlp<<<1, 256, 0, stream>>>(te, wt, bt, tv);

    // ---- GN1 + SiLU -> slot0 slices 0..3 [gn] + 4..7 [raw x] ----
    gn_stats2<128><<<GN_BLOCKS, 256, 0, stream>>>(x, nullptr, gpart);
    gn_reduce<<<1, 256, 0, stream>>>(gpart, stats, GN_BLOCKS);
    gn1_apply<<<3072, 256, 0, stream>>>(x, stats, g1, b1, terms);

    // ---- merged chain: 7 slice-SpMV + fused dual GEMM (w1 slices 0-3, wres 4-7) --
    chain_spmv(stream, chunk, 0, 8, terms, rp, ep);
    {
        dim3 g(V_N / 64 * 2, 2);
        gemm_f16<0, true><<<g, 256, 0, stream>>>(terms, w1f, wrf, 0, 0, 1024, 2,
                                                 nullptr, out, resbuf);
    }

    // ---- GN2(h1 + tv) + SiLU -> terms slot0 (slices 0..7) ----
    gn_stats2<256><<<GN_BLOCKS, 256, 0, stream>>>(out, tv, gpart);
    gn_reduce<<<1, 256, 0, stream>>>(gpart, stats, GN_BLOCKS);
    gn2_apply<<<6144, 256, 0, stream>>>(out, tv, stats, g2, b2, terms);

    // ---- conv2 chain: 7 slice-SpMV + GEMM with fused residual bias ----
    chain_spmv(stream, chunk, 0, 8, terms, rp, ep);
    {
        dim3 g(V_N / 64 * 2);
        gemm_f16<2, false><<<g, 256, 0, stream>>>(terms, w2f, nullptr, 0, 0, 2048, 3,
                                                  resbuf, out, nullptr);
    }
}

// Round 17
// 795.018 us; speedup vs baseline: 1.0067x; 1.0067x over previous
//
#include <hip/hip_runtime.h>
#include <cstddef>

#define V_N 49152
#define E_N 442368
#define E_PAD 589824   // E_N + 3*V_N: worst-case row padding to multiple of 4
#define GEPS 1e-5f
#define CO 256
#define TD 256

typedef _Float16 h16;
typedef _Float16 h8v __attribute__((ext_vector_type(8)));
typedef float f4v __attribute__((ext_vector_type(4)));

// terms layout: [slot][slice(8)][V][32ch], quad q of vertex v stored at
// 16B-slot (q ^ ((v>>1)&3)) within the 64B row. Swizzle sites: gn*_apply
// write, spmv gather/write, GEMM ds_read (fq ^ ((fr>>1)&3)) -- all matched.

__device__ __forceinline__ void gload_lds16(const void* g, void* l) {
    __builtin_amdgcn_global_load_lds(
        (const __attribute__((address_space(1))) unsigned int*)g,
        (__attribute__((address_space(3))) unsigned int*)l, 16, 0, 0);
}

// ---------------- CSR build ----------------
__global__ void count_edges(const int* __restrict__ row, int* __restrict__ cnt) {
    int e = blockIdx.x * blockDim.x + threadIdx.x;
    if (e < E_N) atomicAdd(&cnt[row[e]], 1);
}

// rows padded to multiple of 4 edges (pad slots pre-zeroed in ep)
__global__ void scan_rowptr(int* __restrict__ cnt, int* __restrict__ rowptr) {
    __shared__ int part[1024];
    const int CHUNK = V_N / 1024;  // 48
    int t = threadIdx.x;
    int base = t * CHUNK;
    int s = 0;
    for (int i = 0; i < CHUNK; ++i) s += (cnt[base + i] + 3) & ~3;
    part[t] = s;
    __syncthreads();
    for (int off = 1; off < 1024; off <<= 1) {
        int v = part[t];
        int add = (t >= off) ? part[t - off] : 0;
        __syncthreads();
        part[t] = v + add;
        __syncthreads();
    }
    int run = (t == 0) ? 0 : part[t - 1];
    for (int i = 0; i < CHUNK; ++i) {
        int c = cnt[base + i];
        rowptr[base + i] = run;
        cnt[base + i] = run;   // cursor init for fill pass
        run += (c + 3) & ~3;
    }
    if (t == 1023) rowptr[V_N] = run;
}

// packed edge: {col, val bits} -> one 8B slot per edge
__global__ void fill_csr(const int* __restrict__ row, const int* __restrict__ col,
                         const float* __restrict__ vals, int* __restrict__ cursor,
                         int2* __restrict__ ep) {
    int e = blockIdx.x * blockDim.x + threadIdx.x;
    if (e < E_N) {
        int r = row[e];
        int slot = atomicAdd(&cursor[r], 1);
        ep[slot] = make_int2(col[e], __float_as_int(vals[e]));
    }
}

// ---------------- weight prep: w[k][c][f] fp32 -> MFMA fragment order -------------
// wf[kstep][ntile][lane][8]: lane=(fq<<4)|fr holds w[ks*32+fq*8+j][nt*16+fr].
__global__ void wprep_frag(const float* __restrict__ w, h16* __restrict__ wf) {
    int ks = blockIdx.x, nt = blockIdx.y, lane = threadIdx.x;
    int fr = lane & 15, fq = lane >> 4;
    int f = nt * 16 + fr;
    h8v o;
#pragma unroll
    for (int jj = 0; jj < 8; ++jj) {
        int kc = ks * 32 + fq * 8 + jj;
        o[jj] = (h16)w[(size_t)kc * CO + f];
    }
    *(h8v*)&wf[(((size_t)ks * 16 + nt) * 64 + lane) * 8] = o;
}

// ---------------- GroupNorm stats (register accumulation, per-block partials) ----
template <int C>
__global__ void gn_stats2(const float* __restrict__ x, const float* __restrict__ tvec,
                          float* __restrict__ part) {
    __shared__ float ls[8], lss[8];
    int t = threadIdx.x;
    if (t < 8) { ls[t] = 0.f; lss[t] = 0.f; }
    __syncthreads();
    const int total4 = V_N * (C / 4);
    const int cmask = (C / 4) - 1;
    const int stride = gridDim.x * blockDim.x;  // multiple of 64
    int i0 = blockIdx.x * blockDim.x + t;
    const int c4 = i0 & cmask;  // constant across the loop
    float t0 = 0.f, t1 = 0.f, t2 = 0.f, t3 = 0.f;
    if (tvec) {
        t0 = tvec[c4 * 4 + 0]; t1 = tvec[c4 * 4 + 1];
        t2 = tvec[c4 * 4 + 2]; t3 = tvec[c4 * 4 + 3];
    }
    float s = 0.f, ss = 0.f;
    for (int i = i0; i < total4; i += stride) {
        float4 v = ((const float4*)x)[i];
        v.x += t0; v.y += t1; v.z += t2; v.w += t3;
        s  += v.x + v.y + v.z + v.w;
        ss += v.x * v.x + v.y * v.y + v.z * v.z + v.w * v.w;
    }
    constexpr int GL = (C == 128) ? 4 : 8;
#pragma unroll
    for (int off = 1; off < GL; off <<= 1) {
        s  += __shfl_xor(s, off);
        ss += __shfl_xor(ss, off);
    }
    int lane = t & 63;
    if ((lane & (GL - 1)) == 0) {
        int g = c4 >> ((C == 128) ? 2 : 3);
        atomicAdd(&ls[g], s);
        atomicAdd(&lss[g], ss);
    }
    __syncthreads();
    if (t < 16) part[blockIdx.x * 16 + t] = (t < 8) ? ls[t] : lss[t - 8];
}

#define GN_BLOCKS 512

__global__ void gn_reduce(const float* __restrict__ part, float* __restrict__ stats,
                          int nb) {
    __shared__ float acc[16];
    int t = threadIdx.x;  // 256
    if (t < 16) acc[t] = 0.f;
    __syncthreads();
    int idx = t & 15;
    float s = 0.f;
    for (int j = t >> 4; j < nb; j += 16) s += part[j * 16 + idx];
    atomicAdd(&acc[idx], s);
    __syncthreads();
    if (t < 16) stats[t] = acc[t];
}

// ---------------- GN1 apply + SiLU -> slot0 slices 0..3; raw cast -> slices 4..7 --
__global__ void gn1_apply(const float* __restrict__ x, const float* __restrict__ stats,
                          const float* __restrict__ gamma, const float* __restrict__ beta,
                          h16* __restrict__ terms) {
    const float Ng = (float)V_N * 16.f;   // C=128: V*C/8
    const int total = V_N * 16;
    for (int i = blockIdx.x * blockDim.x + threadIdx.x; i < total;
         i += gridDim.x * blockDim.x) {
        int v = i >> 4, c8 = i & 15;
        float4 xa = ((const float4*)x)[v * 32 + c8 * 2];
        float4 xb = ((const float4*)x)[v * 32 + c8 * 2 + 1];
        float in[8] = {xa.x, xa.y, xa.z, xa.w, xb.x, xb.y, xb.z, xb.w};
        h8v o, oc;
#pragma unroll
        for (int j = 0; j < 8; ++j) {
            int c = c8 * 8 + j;
            int g = c >> 4;
            float mu = stats[g] / Ng;
            float var = stats[8 + g] / Ng - mu * mu;
            float rs = rsqrtf(var + GEPS);
            float y = (in[j] - mu) * rs * gamma[c] + beta[c];
            y = y / (1.f + expf(-y));
            o[j] = (h16)y;
            oc[j] = (h16)in[j];
        }
        int qsl = ((c8 & 3) ^ ((v >> 1) & 3)) * 8;
        int slice = c8 >> 2;
        *(h8v*)&terms[((size_t)slice * V_N + v) * 32 + qsl] = o;
        *(h8v*)&terms[((size_t)(4 + slice) * V_N + v) * 32 + qsl] = oc;
    }
}

// ---------------- GN2 apply + SiLU -> slot0 slices 0..7 (full 256) ----------------
__global__ void gn2_apply(const float* __restrict__ x, const float* __restrict__ tvec,
                          const float* __restrict__ stats, const float* __restrict__ gamma,
                          const float* __restrict__ beta, h16* __restrict__ terms) {
    const float Ng = (float)V_N * 32.f;   // C=256: V*C/8
    const int total = V_N * 32;
    for (int i = blockIdx.x * blockDim.x + threadIdx.x; i < total;
         i += gridDim.x * blockDim.x) {
        int v = i >> 5, c8 = i & 31;
        float4 xa = ((const float4*)x)[v * 64 + c8 * 2];
        float4 xb = ((const float4*)x)[v * 64 + c8 * 2 + 1];
        float in[8] = {xa.x, xa.y, xa.z, xa.w, xb.x, xb.y, xb.z, xb.w};
        h8v o;
#pragma unroll
        for (int j = 0; j < 8; ++j) {
            int c = c8 * 8 + j;
            int g = c >> 5;
            float mu = stats[g] / Ng;
            float var = stats[8 + g] / Ng - mu * mu;
            float rs = rsqrtf(var + GEPS);
            float val = in[j] + tvec[c];
            float y = (val - mu) * rs * gamma[c] + beta[c];
            y = y / (1.f + expf(-y));
            o[j] = (h16)y;
        }
        int qsl = ((c8 & 3) ^ ((v >> 1) & 3)) * 8;
        int slice = c8 >> 2;
        *(h8v*)&terms[((size_t)slice * V_N + v) * 32 + qsl] = o;
    }
}

// ---------------- time embedding MLP ----------------
__global__ void time_mlp(const float* __restrict__ te, const float* __restrict__ wt,
                         const float* __restrict__ bt, float* __restrict__ tvec) {
    __shared__ float s[TD];
    int f = threadIdx.x;
    float v = te[f];
    s[f] = v / (1.f + expf(-v));
    __syncthreads();
    float acc = bt[f];
    for (int t = 0; t < TD; ++t) acc += s[t] * wt[t * CO + f];
    tvec[f] = acc;
}

// ---------------- SpMV, slice-parallel XCD-pinned ----------------
// slice = bid&7 (-> XCD bid&7 by round-robin dispatch): slice footprint
// V*64B = 3.1MB fits that XCD's 4MB L2 -> gathers are L2-local.
// 4-lane group per vertex (lane q = quad), 4 edges in flight, NO cross-lane
// reduce. Rows padded to 4 (pad col=0/val=0 -> hot line, contributes 0).
template <bool RECUR>
__global__ void spmv_slice(const int* __restrict__ rowptr, const int2* __restrict__ ep,
                           h16* __restrict__ terms, int zs, int ps, int ds) {
    const int slice = blockIdx.x & 7;
    const int wid = threadIdx.x >> 6, lane = threadIdx.x & 63;
    const int eg = lane >> 2, q = lane & 3;
    const int v = (blockIdx.x >> 3) * 64 + wid * 16 + eg;
    const h16* zb = terms + ((size_t)(zs * 8 + slice) * V_N) * 32;
    h16* db = terms + ((size_t)(ds * 8 + slice) * V_N) * 32;
    int s = rowptr[v], e = rowptr[v + 1];   // multiples of 4
    float acc[8];
#pragma unroll
    for (int i = 0; i < 8; ++i) acc[i] = 0.f;
    const int4* e4 = (const int4*)(ep + s);  // aligned (s % 4 == 0)
    int n4 = (e - s) >> 1;                   // int4 count (multiple of 2)
    for (int i = 0; i < n4; i += 2) {
        int4 a0 = e4[i], a1 = e4[i + 1];
        h8v z0 = *(const h8v*)&zb[(size_t)a0.x * 32 + ((q ^ ((a0.x >> 1) & 3)) * 8)];
        h8v z1 = *(const h8v*)&zb[(size_t)a0.z * 32 + ((q ^ ((a0.z >> 1) & 3)) * 8)];
        h8v z2 = *(const h8v*)&zb[(size_t)a1.x * 32 + ((q ^ ((a1.x >> 1) & 3)) * 8)];
        h8v z3 = *(const h8v*)&zb[(size_t)a1.z * 32 + ((q ^ ((a1.z >> 1) & 3)) * 8)];
        float v0 = __int_as_float(a0.y), v1 = __int_as_float(a0.w);
        float v2 = __int_as_float(a1.y), v3 = __int_as_float(a1.w);
#pragma unroll
        for (int k = 0; k < 8; ++k)
            acc[k] += v0 * (float)z0[k] + v1 * (float)z1[k] +
                      v2 * (float)z2[k] + v3 * (float)z3[k];
    }
    size_t base = (size_t)v * 32 + ((q ^ ((v >> 1) & 3)) * 8);
    h8v o;
    if (RECUR) {
        const h16* pb = terms + ((size_t)(ps * 8 + slice) * V_N) * 32;
        h8v pv = *(const h8v*)&pb[base];
#pragma unroll
        for (int i = 0; i < 8; ++i) o[i] = (h16)(2.f * acc[i] - (float)pv[i]);
    } else {
#pragma unroll
        for (int i = 0; i < 8; ++i) o[i] = (h16)acc[i];
    }
    *(h8v*)&db[base] = o;
}

// ---------------- MFMA fp16 GEMM: 128x256 tile (N UNSPLIT), 8 waves --------------
// r16 isolated the GEMM as VMEM-BYTES-bound (occupancy 27->50% at same dur).
// Traffic model: A-traffic = #N-tiles x 201MB, B-traffic = #M-tiles x 1MB.
// N unsplit (256) halves A-traffic (402->201MB); each of the 8 waves owns a
// UNIQUE 32-col slice -> zero intra-block B redundancy. Total ~600 vs 800MB.
// acc 8x2 f4v = 64 VGPR; __launch_bounds__(512,4) -> <=128 VGPR, 2 blocks/CU
// (16 waves, inside the proven occupancy-insensitive band). LDS 2x8KB.
// MODE: 0 = store, 1 = accumulate, 2 = out = bias + acc (residual fuse).
// DUAL: blockIdx.y==1 -> slices 4..7 (raw-x half), Wf2, out2.
template <int MODE, bool DUAL>
__global__ __launch_bounds__(512, 4) void gemm_f16(
    const h16* __restrict__ terms, const h16* __restrict__ Wf,
    const h16* __restrict__ Wf2, int kslot0, int wofs, int KC, int slsh,
    const float* __restrict__ bias, float* __restrict__ out,
    float* __restrict__ out2) {
    __shared__ h16 As[2][128 * 32];
    int sofs = 0;
    if (DUAL && blockIdx.y) { Wf = Wf2; out = out2; sofs = 4; }
    const int m0 = blockIdx.x * 128;       // 384 M-panels, N = full 256
    const int tid = threadIdx.x;
    const int wid = tid >> 6, lane = tid & 63;   // 8 waves
    const int fr = lane & 15, fq = lane >> 4;
    const int smsk = (1 << slsh) - 1;
    const h16* Wlane = Wf + ((size_t)(wofs >> 5) * 16 * 512) + (size_t)lane * 8;
    const int ntb = wid * 2;               // wave owns cols [wid*32, wid*32+32)

    f4v acc[8][2];
#pragma unroll
    for (int i = 0; i < 8; ++i)
#pragma unroll
        for (int n = 0; n < 2; ++n) acc[i][n] = (f4v){0.f, 0.f, 0.f, 0.f};

    const int nt = KC >> 5;
    auto stageA = [&](int t, int buf) {
        int r8 = (kslot0 + (t >> slsh)) * 8 + ((t & smsk) + sofs);
        const h16* b = terms + ((size_t)r8 * V_N + m0) * 32;
        // wave wid stages rows [wid*16, wid*16+16): 1KB contiguous
        gload_lds16(b + (size_t)(wid * 16) * 32 + lane * 8, &As[buf][(wid * 16) * 32]);
    };
    h8v bfc[2], bfn[2];
    stageA(0, 0);
#pragma unroll
    for (int n = 0; n < 2; ++n)
        bfc[n] = *(const h8v*)&Wlane[(size_t)(ntb + n) * 512];
    __syncthreads();

    const int slot = (fq ^ ((fr >> 1) & 3)) * 8;
    for (int t = 0; t < nt; ++t) {
        const int cur = t & 1;
        int tn = (t + 1 < nt) ? t + 1 : t;
        stageA(tn, cur ^ 1);
#pragma unroll
        for (int n = 0; n < 2; ++n)
            bfn[n] = *(const h8v*)&Wlane[((size_t)tn * 16 + ntb + n) * 512];
        // process M in 2 chunks of 4 frags to bound live af registers
#pragma unroll
        for (int h = 0; h < 2; ++h) {
            h8v af[4];
#pragma unroll
            for (int i = 0; i < 4; ++i)
                af[i] = *(const h8v*)&As[cur][((h * 4 + i) * 16 + fr) * 32 + slot];
#pragma unroll
            for (int i = 0; i < 4; ++i)
#pragma unroll
                for (int n = 0; n < 2; ++n)
                    acc[h * 4 + i][n] = __builtin_amdgcn_mfma_f32_16x16x32_f16(
                        af[i], bfc[n], acc[h * 4 + i][n], 0, 0, 0);
        }
        __syncthreads();
#pragma unroll
        for (int n = 0; n < 2; ++n) bfc[n] = bfn[n];
    }
#pragma unroll
    for (int i = 0; i < 8; ++i)
#pragma unroll
        for (int n = 0; n < 2; ++n)
#pragma unroll
            for (int rr = 0; rr < 4; ++rr) {
                int row = m0 + i * 16 + fq * 4 + rr;
                int col = wid * 32 + n * 16 + fr;
                size_t idx = (size_t)row * CO + col;
                if (MODE == 0) out[idx] = acc[i][n][rr];
                else if (MODE == 1) out[idx] += acc[i][n][rr];
                else out[idx] = bias[idx] + acc[i][n][rr];
            }
}

// ---------------- host orchestration ----------------
static void chain_spmv(hipStream_t s, int chunk, int k0, int kend, h16* terms,
                       const int* rp, const int2* ep) {
    for (int k = (k0 == 0 ? 1 : k0); k < kend; ++k) {
        int zs = (k - 1) % chunk, ds = k % chunk;
        if (k == 1) {
            spmv_slice<false><<<V_N / 64 * 8, 256, 0, s>>>(rp, ep, terms, zs, 0, ds);
        } else {
            int ps = (k - 2) % chunk;
            spmv_slice<true><<<V_N / 64 * 8, 256, 0, s>>>(rp, ep, terms, zs, ps, ds);
        }
    }
}

extern "C" void kernel_launch(void* const* d_in, const int* in_sizes, int n_in,
                              void* d_out, int out_size, void* d_ws, size_t ws_size,
                              hipStream_t stream) {
    const float* x    = (const float*)d_in[0];
    const float* te   = (const float*)d_in[1];
    const int*   row  = (const int*)d_in[2];
    const int*   col  = (const int*)d_in[3];
    const float* vals = (const float*)d_in[4];
    const float* wres = (const float*)d_in[5];
    const float* w1   = (const float*)d_in[6];
    const float* w2   = (const float*)d_in[7];
    const float* g1   = (const float*)d_in[8];
    const float* b1   = (const float*)d_in[9];
    const float* g2   = (const float*)d_in[10];
    const float* b2   = (const float*)d_in[11];
    const float* wt   = (const float*)d_in[12];
    const float* bt   = (const float*)d_in[13];
    float* out = (float*)d_out;

    const int chunk = 8;
    const size_t slot_b = (size_t)V_N * 256 * 2;          // 25.2 MB per k-slot
    const size_t res_b  = (size_t)V_N * 256 * 4;          // 50.3 MB
    const size_t csr_b  = (size_t)(V_N + V_N + 1) * 4 + (size_t)E_PAD * 8;
    const size_t wt_b   = (size_t)(1024 + 2048 + 1024) * CO * 2;
    const size_t misc_b = 8192 + (size_t)GN_BLOCKS * 16 * 4;
    if (ws_size < (size_t)chunk * slot_b + res_b + csr_b + wt_b + misc_b) return;

    char* p = (char*)d_ws;
    h16* terms = (h16*)p;              p += (size_t)chunk * slot_b;
    float* resbuf = (float*)p;         p += res_b;
    h16* w1f = (h16*)p;                p += (size_t)1024 * CO * 2;
    h16* w2f = (h16*)p;                p += (size_t)2048 * CO * 2;
    h16* wrf = (h16*)p;                p += (size_t)1024 * CO * 2;
    int* cnt = (int*)p;                p += (size_t)V_N * 4;
    int* rp  = (int*)p;                p += (size_t)(V_N + 1) * 4;
    int2* ep = (int2*)p;               p += (size_t)E_PAD * 8;
    float* stats = (float*)p;          p += 64;
    float* tv = (float*)p;             p += 1024;
    float* gpart = (float*)p;          p += (size_t)GN_BLOCKS * 16 * 4;

    // CSR build (rows padded to multiple of 4; pad slots are {0, 0.0f})
    hipMemsetAsync(cnt, 0, V_N * sizeof(int), stream);
    hipMemsetAsync(ep, 0, (size_t)E_PAD * 8, stream);
    count_edges<<<E_N / 256, 256, 0, stream>>>(row, cnt);
    scan_rowptr<<<1, 1024, 0, stream>>>(cnt, rp);
    fill_csr<<<E_N / 256, 256, 0, stream>>>(row, col, vals, cnt, ep);

    // weight prep: MFMA fragment order
    wprep_frag<<<dim3(32, 16), 64, 0, stream>>>(w1, w1f);
    wprep_frag<<<dim3(64, 16), 64, 0, stream>>>(w2, w2f);
    wprep_frag<<<dim3(32, 16), 64, 0, stream>>>(wres, wrf);

    // time embedding
    time_mlp<<<1, 256, 0, stream>>>(te, wt, bt, tv);

    // ---- GN1 + SiLU -> slot0 slices 0..3 [gn] + 4..7 [raw x] ----
    gn_stats2<128><<<GN_BLOCKS, 256, 0, stream>>>(x, nullptr, gpart);
    gn_reduce<<<1, 256, 0, stream>>>(gpart, stats, GN_BLOCKS);
    gn1_apply<<<3072, 256, 0, stream>>>(x, stats, g1, b1, terms);

    // ---- merged chain: 7 slice-SpMV + fused dual GEMM (w1 slices 0-3, wres 4-7) --
    chain_spmv(stream, chunk, 0, 8, terms, rp, ep);
    {
        dim3 g(V_N / 128, 2);
        gemm_f16<0, true><<<g, 512, 0, stream>>>(terms, w1f, wrf, 0, 0, 1024, 2,
                                                 nullptr, out, resbuf);
    }

    // ---- GN2(h1 + tv) + SiLU -> terms slot0 (slices 0..7) ----
    gn_stats2<256><<<GN_BLOCKS, 256, 0, stream>>>(out, tv, gpart);
    gn_reduce<<<1, 256, 0, stream>>>(gpart, stats, GN_BLOCKS);
    gn2_apply<<<6144, 256, 0, stream>>>(out, tv, stats, g2, b2, terms);

    // ---- conv2 chain: 7 slice-SpMV + GEMM with fused residual bias ----
    chain_spmv(stream, chunk, 0, 8, terms, rp, ep);
    {
        dim3 g(V_N / 128);
        gemm_f16<2, false><<<g, 512, 0, stream>>>(terms, w2f, nullptr, 0, 0, 2048, 3,
                                                  resbuf, out, nullptr);
    }
}